// Round 1
// baseline (568.937 us; speedup 1.0000x reference)
//
#include <hip/hip_runtime.h>

#define BATCH   32768
#define VOLUME  4096   // 8*8*8*8
#define NBLK    (BATCH / 64)

__global__ __launch_bounds__(64) void interp4d_kernel(
    const float* __restrict__ coords,   // [B,4]
    const float* __restrict__ mesh,     // [B,VOLUME]
    float* __restrict__ out)            // [B]
{
    const int b = blockIdx.x * 64 + threadIdx.x;
    if (b >= BATCH) return;

    // Coalesced 16B coordinate load
    const float4 c4 = *reinterpret_cast<const float4*>(coords + (size_t)b * 4);

    const float c0 = c4.x * 7.0f;
    const float c1 = c4.y * 7.0f;
    const float c2 = c4.z * 7.0f;
    const float c3 = c4.w * 7.0f;

    // trunc (coords >= 0) then clamp to [0, 6]
    int i0 = (int)c0; i0 = i0 < 0 ? 0 : (i0 > 6 ? 6 : i0);
    int i1 = (int)c1; i1 = i1 < 0 ? 0 : (i1 > 6 ? 6 : i1);
    int i2 = (int)c2; i2 = i2 < 0 ? 0 : (i2 > 6 ? 6 : i2);
    int i3 = (int)c3; i3 = i3 < 0 ? 0 : (i3 > 6 ? 6 : i3);

    const float f0 = c0 - (float)i0;
    const float f1 = c1 - (float)i1;
    const float f2 = c2 - (float)i2;
    const float f3 = c3 - (float)i3;

    const float* __restrict__ base =
        mesh + (size_t)b * VOLUME + i0 * 512 + i1 * 64 + i2 * 8 + i3;

    // 16 independent gathers — issued back-to-back, one vmcnt wait
    float v[16];
#pragma unroll
    for (int a = 0; a < 2; ++a)
#pragma unroll
        for (int bb = 0; bb < 2; ++bb)
#pragma unroll
            for (int cc = 0; cc < 2; ++cc)
#pragma unroll
                for (int d = 0; d < 2; ++d)
                    v[a * 8 + bb * 4 + cc * 2 + d] =
                        base[a * 512 + bb * 64 + cc * 8 + d];

    const float w0[2] = {1.0f - f0, f0};
    const float w1[2] = {1.0f - f1, f1};
    const float w2[2] = {1.0f - f2, f2};
    const float w3[2] = {1.0f - f3, f3};

    float acc = 0.0f;
#pragma unroll
    for (int a = 0; a < 2; ++a)
#pragma unroll
        for (int bb = 0; bb < 2; ++bb)
#pragma unroll
            for (int cc = 0; cc < 2; ++cc)
#pragma unroll
                for (int d = 0; d < 2; ++d)
                    acc += v[a * 8 + bb * 4 + cc * 2 + d] *
                           (w0[a] * w1[bb] * w2[cc] * w3[d]);

    out[b] = acc;
}

extern "C" void kernel_launch(void* const* d_in, const int* in_sizes, int n_in,
                              void* d_out, int out_size, void* d_ws, size_t ws_size,
                              hipStream_t stream) {
    const float* coords = (const float*)d_in[0];   // [32768, 4]
    const float* mesh   = (const float*)d_in[1];   // [32768, 4096]
    float* out          = (float*)d_out;           // [32768]

    interp4d_kernel<<<NBLK, 64, 0, stream>>>(coords, mesh, out);
}

// Round 2
// 567.432 us; speedup vs baseline: 1.0027x; 1.0027x over previous
//
#include <hip/hip_runtime.h>

#define BATCH   32768
#define VOLUME  4096            // 8*8*8*8
#define TPR     8               // threads per row (one per a,b,c corner combo)
#define NTHREADS (BATCH * TPR)  // 262144
#define BLOCK   256
#define NBLK    (NTHREADS / BLOCK)  // 1024 blocks -> 4096 waves -> 16 waves/CU

__global__ __launch_bounds__(BLOCK) void interp4d_kernel(
    const float* __restrict__ coords,   // [B,4]
    const float* __restrict__ mesh,     // [B,VOLUME]
    float* __restrict__ out)            // [B]
{
    const int t = blockIdx.x * BLOCK + threadIdx.x;
    const int r = t >> 3;       // row
    const int k = t & 7;        // corner group: bits (a,b,c)

    // 8 lanes share one row -> float4 load is broadcast within the group,
    // 8 distinct consecutive float4s per wave (2 cache lines).
    const float4 c4 = *reinterpret_cast<const float4*>(coords + (size_t)r * 4);

    const float c0 = c4.x * 7.0f;
    const float c1 = c4.y * 7.0f;
    const float c2 = c4.z * 7.0f;
    const float c3 = c4.w * 7.0f;

    int i0 = (int)c0; i0 = i0 < 0 ? 0 : (i0 > 6 ? 6 : i0);
    int i1 = (int)c1; i1 = i1 < 0 ? 0 : (i1 > 6 ? 6 : i1);
    int i2 = (int)c2; i2 = i2 < 0 ? 0 : (i2 > 6 ? 6 : i2);
    int i3 = (int)c3; i3 = i3 < 0 ? 0 : (i3 > 6 ? 6 : i3);

    const float f0 = c0 - (float)i0;
    const float f1 = c1 - (float)i1;
    const float f2 = c2 - (float)i2;
    const float f3 = c3 - (float)i3;

    const int a  = (k >> 2) & 1;
    const int bb = (k >> 1) & 1;
    const int cc = k & 1;

    const float* __restrict__ p =
        mesh + (size_t)r * VOLUME + (i0 + a) * 512 + (i1 + bb) * 64 + (i2 + cc) * 8 + i3;

    // Innermost-dim pair (adjacent floats). Two dword loads, issued together.
    const float v0 = p[0];
    const float v1 = p[1];

    const float w = (a  ? f0 : 1.0f - f0) *
                    (bb ? f1 : 1.0f - f1) *
                    (cc ? f2 : 1.0f - f2);

    float partial = w * (v0 * (1.0f - f3) + v1 * f3);

    // Reduce the 8 corner-lanes of this row (xor masks stay within the group).
    partial += __shfl_xor(partial, 1);
    partial += __shfl_xor(partial, 2);
    partial += __shfl_xor(partial, 4);

    if (k == 0) out[r] = partial;
}

extern "C" void kernel_launch(void* const* d_in, const int* in_sizes, int n_in,
                              void* d_out, int out_size, void* d_ws, size_t ws_size,
                              hipStream_t stream) {
    const float* coords = (const float*)d_in[0];   // [32768, 4]
    const float* mesh   = (const float*)d_in[1];   // [32768, 4096]
    float* out          = (float*)d_out;           // [32768]

    interp4d_kernel<<<NBLK, BLOCK, 0, stream>>>(coords, mesh, out);
}